// Round 17
// baseline (485.008 us; speedup 1.0000x reference)
//
#include <hip/hip_runtime.h>
#include <hip/hip_bf16.h>
#include <stdint.h>

#define NDEC 8192
#define NENC 8192
#define IND  512
#define OUTD 64
#define NSPLIT 8
#define CHUNK  1024         // NENC / NSPLIT
#define NITER  16           // CHUNK / 64

typedef __attribute__((ext_vector_type(8))) short bf16x8;
typedef __attribute__((ext_vector_type(4))) float f32x4;
typedef __attribute__((ext_vector_type(16))) float f32x16;

static __device__ __forceinline__ uint32_t pkbf(float a, float b) {
    union { __hip_bfloat162 h; uint32_t u; } c;
    c.h = __float22bfloat162_rn(make_float2(a, b));   // v_cvt_pk_bf16_f32
    return c.u;
}
static __device__ __forceinline__ unsigned short f2bfu(float f) {
    union { __hip_bfloat16 h; unsigned short u; } c;
    c.h = __float2bfloat16(f);
    return c.u;
}
static __device__ __forceinline__ bf16x8 cvt8(float4 a, float4 b) {
    union { uint32_t u[4]; bf16x8 v; } r;
    r.u[0] = pkbf(a.x, a.y); r.u[1] = pkbf(a.z, a.w);
    r.u[2] = pkbf(b.x, b.y); r.u[3] = pkbf(b.z, b.w);
    return r.v;
}
// sigma: involutive permutation on bits[3:2] (01 <-> 10), identity elsewhere.
static __device__ __forceinline__ int sig4(int u) {
    return (u & ~12) | ((u & 4) << 1) | ((u & 8) >> 1);
}
// LDS tile swizzle (attn): (row, c) -> byte offset; c in 16B units.
static __device__ __forceinline__ int swz(int row, int c) {
    return (row << 7) + ((c ^ (row & 7)) << 4);
}
// proj A-tile swizzle: row-major [32][512] bf16, byte ^= (row&7)<<4.
static __device__ __forceinline__ int aswz(int row, int k2) {
    return (row << 10) + (k2 ^ ((row & 7) << 4));
}

// ---------------------------------------------------------------------------
// Stage 0: prep (r13-proven). Wq*c, Wk -> WT2 fragment-coalesced; Wv -> WTv.
// ---------------------------------------------------------------------------
__global__ __launch_bounds__(256) void prep_kernel(
    const float* __restrict__ wq, const float* __restrict__ wk, const float* __restrict__ wv,
    unsigned short* __restrict__ WT2, unsigned short* __restrict__ WTv)
{
    int idx = blockIdx.x * 256 + threadIdx.x;
    int mat = idx >> 15;
    int r = idx & 32767;                        // k*64 + n
    int k = r >> 6, n = r & 63;
    const float* W = (mat == 0) ? wq : ((mat == 1) ? wk : wv);
    float s = (mat == 0) ? 0.18033688011112042f : 1.0f;  // 0.125*log2(e)
    unsigned short v = f2bfu(W[r] * s);
    if (mat < 2)
        WT2[mat * 32768 + (((k >> 3) * 64 + n) << 3) + (k & 7)] = v;
    else
        WTv[n * 512 + k] = v;
}

// ---------------------------------------------------------------------------
// Stage 1: projections (r13-proven, unchanged).
// ---------------------------------------------------------------------------
__global__ __launch_bounds__(256) void proj_kernel(
    const float* __restrict__ x, const float* __restrict__ emb,
    const unsigned short* __restrict__ WT2, const unsigned short* __restrict__ WTv,
    unsigned short* __restrict__ qbuf, unsigned short* __restrict__ kbuf,
    unsigned short* __restrict__ vTt)
{
    __shared__ char at[32768];   // 32 rows x 512 bf16, swizzled
    const int t = threadIdx.x;
    const bool isq = blockIdx.x < 256;
    const int tile = isq ? blockIdx.x : blockIdx.x - 256;
    const float* A = isq ? x : emb;
    const int rbase = tile * 32;
    const int wave = t >> 6, lane = t & 63;
    const int lo = lane & 15, g = lane >> 4;

    #pragma unroll 4
    for (int i = 0; i < 8; ++i) {
        int pidx = i * 256 + t;
        int row = pidx >> 6, c = pidx & 63;
        const float* src = A + (size_t)(rbase + row) * IND + c * 8;
        float4 a0 = *(const float4*)src;
        float4 a1 = *(const float4*)(src + 4);
        *(bf16x8*)(at + aswz(row, c * 16)) = cvt8(a0, a1);
    }
    __syncthreads();

    {
        const int wr = wave >> 1, wc = wave & 1;
        const unsigned short* WT = WT2 + (isq ? 0 : 32768);
        const int nb = wc * 32 + lo;
        f32x4 acc[2];
        acc[0] = (f32x4){0.f, 0.f, 0.f, 0.f};
        acc[1] = (f32x4){0.f, 0.f, 0.f, 0.f};
        bf16x8 wf[2];
        #pragma unroll
        for (int nfi = 0; nfi < 2; ++nfi)
            wf[nfi] = *(const bf16x8*)(WT + ((g * 64) + nb + nfi * 16) * 8);
        #pragma unroll
        for (int ks = 0; ks < 16; ++ks) {
            bf16x8 wn[2] = {wf[0], wf[1]};
            if (ks < 15) {
                #pragma unroll
                for (int nfi = 0; nfi < 2; ++nfi)
                    wn[nfi] = *(const bf16x8*)(WT + (((ks + 1) * 4 + g) * 64 + nb + nfi * 16) * 8);
            }
            bf16x8 af = *(const bf16x8*)(at + aswz(wr * 16 + lo, (ks * 32 + g * 8) * 2));
            #pragma unroll
            for (int nfi = 0; nfi < 2; ++nfi)
                acc[nfi] = __builtin_amdgcn_mfma_f32_16x16x32_bf16(af, wf[nfi], acc[nfi], 0, 0, 0);
            wf[0] = wn[0]; wf[1] = wn[1];
        }
        unsigned short* obuf = isq ? qbuf : kbuf;
        #pragma unroll
        for (int nfi = 0; nfi < 2; ++nfi)
            #pragma unroll
            for (int r = 0; r < 4; ++r)
                obuf[(size_t)(rbase + wr * 16 + 4 * g + r) * OUTD + (wc * 2 + nfi) * 16 + lo] = f2bfu(acc[nfi][r]);
    }

    if (!isq) {
        const int f = wave * 16 + lo;
        f32x4 acc[2];
        acc[0] = (f32x4){0.f, 0.f, 0.f, 0.f};
        acc[1] = (f32x4){0.f, 0.f, 0.f, 0.f};
        bf16x8 wf = *(const bf16x8*)(WTv + f * 512 + g * 8);
        #pragma unroll
        for (int ks = 0; ks < 16; ++ks) {
            bf16x8 wn = wf;
            if (ks < 15) wn = *(const bf16x8*)(WTv + f * 512 + (ks + 1) * 32 + g * 8);
            const int k0 = ks * 32 + g * 8;
            #pragma unroll
            for (int nfi = 0; nfi < 2; ++nfi) {
                bf16x8 ef = *(const bf16x8*)(at + aswz(nfi * 16 + lo, k0 * 2));
                acc[nfi] = __builtin_amdgcn_mfma_f32_16x16x32_bf16(wf, ef, acc[nfi], 0, 0, 0);
            }
            wf = wn;
        }
        const int lop = sig4(lo);
        unsigned short* vblk = vTt + (size_t)(rbase >> 6) * 4096 + ((rbase >> 5) & 1) * 32;
        #pragma unroll
        for (int nfi = 0; nfi < 2; ++nfi)
            #pragma unroll
            for (int r = 0; r < 4; ++r)
                vblk[(wave * 16 + 4 * g + r) * 64 + nfi * 16 + lop] = f2bfu(acc[nfi][r]);
    }
}

// ---------------------------------------------------------------------------
// Stage 2: flash attention, 2-WAVE BLOCKS (128 thr, 64 q-rows), 4 blocks/CU.
// K: 2-buffer rotation [0,16K); V: 3-buffer rotation [16K,40K). Pipelined:
// QK(it) in flight while SOFTPV(it-1) runs; WRITET after. Barriers sync only
// 2 waves; 4 independent block streams/CU. Fixed softmax shift, VALU row-sum.
// PASSES>1 = probe mode (dummy outputs; per-pass data stale but deterministic).
// ---------------------------------------------------------------------------
template<int PASSES>
__global__ __launch_bounds__(128) void attn_core(
    const unsigned short* __restrict__ qbuf, const unsigned short* __restrict__ kbuf,
    const unsigned short* __restrict__ vTt,
    unsigned short* __restrict__ Opart, float* __restrict__ Lpart)
{
    __shared__ char lds[40960];   // K: 2 x 8K at 0,8192; V: 3 x 8K at 16384+
    const int t = threadIdx.x;
    const int wave = t >> 6, lane = t & 63;
    const int r32 = lane & 31, hi = lane >> 5;
    const int qrow = blockIdx.x * 64 + wave * 32 + r32;
    const int split = blockIdx.y;
    const int tok0 = split * CHUNK;

    bf16x8 qf[4];
    #pragma unroll
    for (int kt = 0; kt < 4; ++kt)
        qf[kt] = *(const bf16x8*)(qbuf + (size_t)qrow * OUTD + kt * 16 + hi * 8);

    f32x16 o0 = (f32x16)(0.f), o1 = (f32x16)(0.f);
    float l_run = 0.f;

    uint4 ak[4], av[4];
    auto LOADT = [&](int tb) {
        const uint4* ks = (const uint4*)(kbuf + (size_t)tb * 64);
        const uint4* vs = (const uint4*)(vTt + (size_t)tb * 64);
        #pragma unroll
        for (int r = 0; r < 4; ++r) { ak[r] = ks[r * 128 + t]; av[r] = vs[r * 128 + t]; }
    };
    auto WRITET = [&](char* kb, char* vb) {
        #pragma unroll
        for (int r = 0; r < 4; ++r) {
            int j = r * 128 + t;
            *(uint4*)(kb + swz(j >> 3, j & 7)) = ak[r];
            *(uint4*)(vb + swz(j >> 3, j & 7)) = av[r];
        }
    };
    auto QK = [&](const char* kb, f32x16& sA, f32x16& sB) {
        bf16x8 kA[4], kB[4];
        #pragma unroll
        for (int kt = 0; kt < 4; ++kt) {
            const int c = kt * 2 + hi;
            kA[kt] = *(const bf16x8*)(kb + swz(r32, c));
            kB[kt] = *(const bf16x8*)(kb + swz(32 + r32, c));
        }
        sA = (f32x16)(-16.f); sB = (f32x16)(-16.f);
        __builtin_amdgcn_s_setprio(1);
        #pragma unroll
        for (int kt = 0; kt < 4; ++kt) {
            sA = __builtin_amdgcn_mfma_f32_32x32x16_bf16(kA[kt], qf[kt], sA, 0, 0, 0);
            sB = __builtin_amdgcn_mfma_f32_32x32x16_bf16(kB[kt], qf[kt], sB, 0, 0, 0);
        }
        __builtin_amdgcn_s_setprio(0);
    };
    auto SOFTPV = [&](f32x16& sA, f32x16& sB, const char* vb) {
        #pragma unroll
        for (int r = 0; r < 16; ++r) {
            sA[r] = __builtin_amdgcn_exp2f(sA[r]);
            sB[r] = __builtin_amdgcn_exp2f(sB[r]);
        }
        {
            float a8[8], b8[8], a4[4], b4[4];
            #pragma unroll
            for (int j = 0; j < 8; ++j) {
                a8[j] = sA[2 * j] + sA[2 * j + 1];
                b8[j] = sB[2 * j] + sB[2 * j + 1];
            }
            #pragma unroll
            for (int j = 0; j < 4; ++j) {
                a4[j] = a8[2 * j] + a8[2 * j + 1];
                b4[j] = b8[2 * j] + b8[2 * j + 1];
            }
            l_run += ((a4[0] + a4[1]) + (a4[2] + a4[3]))
                   + ((b4[0] + b4[1]) + (b4[2] + b4[3]));
        }
        union { uint32_t u[4]; bf16x8 v; } pA0, pA1, pB0, pB1;
        #pragma unroll
        for (int j = 0; j < 4; ++j) {
            pA0.u[j] = pkbf(sA[2 * j], sA[2 * j + 1]);
            pA1.u[j] = pkbf(sA[8 + 2 * j], sA[9 + 2 * j]);
            pB0.u[j] = pkbf(sB[2 * j], sB[2 * j + 1]);
            pB1.u[j] = pkbf(sB[8 + 2 * j], sB[9 + 2 * j]);
        }
        bf16x8 vA[4], vB[4];
        #pragma unroll
        for (int ft = 0; ft < 2; ++ft)
            #pragma unroll
            for (int kt = 0; kt < 2; ++kt) {
                const int row = ft * 32 + r32;
                vA[ft * 2 + kt] = *(const bf16x8*)(vb + swz(row, kt * 2 + hi));
                vB[ft * 2 + kt] = *(const bf16x8*)(vb + swz(row, 4 + kt * 2 + hi));
            }
        __builtin_amdgcn_s_setprio(1);
        o0 = __builtin_amdgcn_mfma_f32_32x32x16_bf16(vA[0], pA0.v, o0, 0, 0, 0);
        o1 = __builtin_amdgcn_mfma_f32_32x32x16_bf16(vA[2], pA0.v, o1, 0, 0, 0);
        o0 = __builtin_amdgcn_mfma_f32_32x32x16_bf16(vA[1], pA1.v, o0, 0, 0, 0);
        o1 = __builtin_amdgcn_mfma_f32_32x32x16_bf16(vA[3], pA1.v, o1, 0, 0, 0);
        o0 = __builtin_amdgcn_mfma_f32_32x32x16_bf16(vB[0], pB0.v, o0, 0, 0, 0);
        o1 = __builtin_amdgcn_mfma_f32_32x32x16_bf16(vB[2], pB0.v, o1, 0, 0, 0);
        o0 = __builtin_amdgcn_mfma_f32_32x32x16_bf16(vB[1], pB1.v, o0, 0, 0, 0);
        o1 = __builtin_amdgcn_mfma_f32_32x32x16_bf16(vB[3], pB1.v, o1, 0, 0, 0);
        __builtin_amdgcn_s_setprio(0);
    };

    // prologue: tile0 -> K0/V0; QK(0); tile1 -> K1/V1
    LOADT(tok0);
    WRITET(lds, lds + 16384);
    __syncthreads();
    LOADT(tok0 + 64);
    f32x16 sPA, sPB;
    QK(lds, sPA, sPB);
    WRITET(lds + 8192, lds + 16384 + 8192);

    for (int p = 0; p < PASSES; ++p)
    #pragma unroll
    for (int it = 1; it < NITER; ++it) {
        __syncthreads();
        const bool have = (it + 1 < NITER);
        if (have) LOADT(tok0 + (it + 1) * 64);
        f32x16 sNA, sNB;
        QK(lds + (it % 2) * 8192, sNA, sNB);                     // in flight...
        SOFTPV(sPA, sPB, lds + 16384 + ((it - 1) % 3) * 8192);   // ...while VALU
        if (have) WRITET(lds + ((it + 1) % 2) * 8192,
                         lds + 16384 + ((it + 1) % 3) * 8192);
        sPA = sNA; sPB = sNB;
    }
    SOFTPV(sPA, sPB, lds + 16384 + ((NITER - 1) % 3) * 8192);

    float l = l_run + __shfl_xor(l_run, 32);
    if (hi == 0)
        Lpart[(size_t)split * NDEC + qrow] = l;
    unsigned short* orow = Opart + ((size_t)split * NDEC + qrow) * OUTD;
    #pragma unroll
    for (int q = 0; q < 4; ++q) {
        uint2 st0, st1;
        st0.x = pkbf(o0[q * 4 + 0], o0[q * 4 + 1]);
        st0.y = pkbf(o0[q * 4 + 2], o0[q * 4 + 3]);
        st1.x = pkbf(o1[q * 4 + 0], o1[q * 4 + 1]);
        st1.y = pkbf(o1[q * 4 + 2], o1[q * 4 + 3]);
        *(uint2*)(orow + q * 8 + hi * 4) = st0;
        *(uint2*)(orow + 32 + q * 8 + hi * 4) = st1;
    }
}

// ---------------------------------------------------------------------------
// Stage 3: combine splits and normalize.
// ---------------------------------------------------------------------------
__global__ __launch_bounds__(256) void combine_kernel(
    const unsigned short* __restrict__ Opart, const float* __restrict__ Lpart,
    float* __restrict__ out)
{
    int idx = blockIdx.x * 256 + threadIdx.x;
    int row = idx >> 3;
    int fo = (idx & 7) * 8;
    float L = 0.f;
    float acc[8];
    #pragma unroll
    for (int j = 0; j < 8; ++j) acc[j] = 0.f;
    #pragma unroll
    for (int s = 0; s < NSPLIT; ++s) {
        L += Lpart[(size_t)s * NDEC + row];
        uint4 v = *(const uint4*)(Opart + ((size_t)s * NDEC + row) * OUTD + fo);
        uint32_t u[4] = {v.x, v.y, v.z, v.w};
        #pragma unroll
        for (int j = 0; j < 4; ++j) {
            union { uint32_t u; float f; } lo2, hi2;
            lo2.u = u[j] << 16;
            hi2.u = u[j] & 0xFFFF0000u;
            acc[2 * j]     += lo2.f;
            acc[2 * j + 1] += hi2.f;
        }
    }
    float inv = 1.f / L;
    float4 s0, s1;
    s0.x = acc[0] * inv; s0.y = acc[1] * inv; s0.z = acc[2] * inv; s0.w = acc[3] * inv;
    s1.x = acc[4] * inv; s1.y = acc[5] * inv; s1.z = acc[6] * inv; s1.w = acc[7] * inv;
    *(float4*)(out + (size_t)row * OUTD + fo) = s0;
    *(float4*)(out + (size_t)row * OUTD + fo + 4) = s1;
}

extern "C" void kernel_launch(void* const* d_in, const int* in_sizes, int n_in,
                              void* d_out, int out_size, void* d_ws, size_t ws_size,
                              hipStream_t stream) {
    const float* x   = (const float*)d_in[0];
    const float* emb = (const float*)d_in[1];
    const float* wq  = (const float*)d_in[2];
    const float* wk  = (const float*)d_in[3];
    const float* wv  = (const float*)d_in[4];
    float* out = (float*)d_out;
    char* ws = (char*)d_ws;

    unsigned short* qbuf = (unsigned short*)ws;                          // 1 MiB
    unsigned short* kbuf = (unsigned short*)(ws + (1u << 20));           // 1 MiB
    unsigned short* vTt  = (unsigned short*)(ws + (2u << 20));           // 1 MiB
    unsigned short* WT2  = (unsigned short*)(ws + (3u << 20));           // 128 KiB
    unsigned short* WTv  = (unsigned short*)(ws + (3u << 20) + (128u << 10)); // 64 KiB
    const size_t obase = (3u << 20) + (256u << 10);
    const size_t osz = (size_t)NSPLIT * NDEC * OUTD * 2;                 // 8 MiB
    const size_t lsz = (size_t)NSPLIT * NDEC * 4;                        // 256 KiB
    unsigned short* Opart = (unsigned short*)(ws + obase);
    float* Lpart = (float*)(ws + obase + osz);

    const size_t dbase = obase + osz + lsz;
    unsigned short* dOp = (unsigned short*)(ws + dbase);                 // 8 MiB
    float* dLp = (float*)(ws + dbase + osz);                             // 256 KiB
    const bool do_probe = ws_size >= dbase + osz + lsz;

    hipLaunchKernelGGL(prep_kernel, dim3(384), dim3(256), 0, stream, wq, wk, wv, WT2, WTv);
    hipLaunchKernelGGL(proj_kernel, dim3(512), dim3(256), 0, stream,
                       x, emb, WT2, WTv, qbuf, kbuf, vTt);
    hipLaunchKernelGGL((attn_core<1>), dim3(NDEC / 64, NSPLIT), dim3(128), 0, stream,
                       qbuf, kbuf, vTt, Opart, Lpart);
    hipLaunchKernelGGL(combine_kernel, dim3((NDEC * 8) / 256), dim3(256), 0, stream,
                       Opart, Lpart, out);

    if (do_probe)
        hipLaunchKernelGGL((attn_core<4>), dim3(NDEC / 64, NSPLIT), dim3(128), 0, stream,
                           qbuf, kbuf, vTt, dOp, dLp);
}

// Round 18
// 49.710 us; speedup vs baseline: 9.7567x; 9.7567x over previous
//
#include <hip/hip_runtime.h>
#include <hip/hip_bf16.h>
#include <stdint.h>

#define NDEC 8192
#define NENC 8192
#define IND  512
#define OUTD 64
#define NSPLIT 8
#define CHUNK  1024         // NENC / NSPLIT
#define NITER  16           // CHUNK / 64

typedef __attribute__((ext_vector_type(8))) short bf16x8;
typedef __attribute__((ext_vector_type(4))) float f32x4;
typedef __attribute__((ext_vector_type(16))) float f32x16;

static __device__ __forceinline__ uint32_t pkbf(float a, float b) {
    union { __hip_bfloat162 h; uint32_t u; } c;
    c.h = __float22bfloat162_rn(make_float2(a, b));   // v_cvt_pk_bf16_f32
    return c.u;
}
static __device__ __forceinline__ unsigned short f2bfu(float f) {
    union { __hip_bfloat16 h; unsigned short u; } c;
    c.h = __float2bfloat16(f);
    return c.u;
}
static __device__ __forceinline__ bf16x8 cvt8(float4 a, float4 b) {
    union { uint32_t u[4]; bf16x8 v; } r;
    r.u[0] = pkbf(a.x, a.y); r.u[1] = pkbf(a.z, a.w);
    r.u[2] = pkbf(b.x, b.y); r.u[3] = pkbf(b.z, b.w);
    return r.v;
}
// sigma: involutive permutation on bits[3:2] (01 <-> 10), identity elsewhere.
static __device__ __forceinline__ int sig4(int u) {
    return (u & ~12) | ((u & 4) << 1) | ((u & 8) >> 1);
}
// LDS tile swizzle (attn): (row, c) -> byte offset; c in 16B units.
static __device__ __forceinline__ int swz(int row, int c) {
    return (row << 7) + ((c ^ (row & 7)) << 4);
}
// proj A-tile swizzle: row-major [32][512] bf16, byte ^= (row&7)<<4.
static __device__ __forceinline__ int aswz(int row, int k2) {
    return (row << 10) + (k2 ^ ((row & 7) << 4));
}

// ---------------------------------------------------------------------------
// Stage 0: prep. mats 0,1 (Wq*c, Wk) -> WT2 fragment-coalesced: (k,n) at
// ((k>>3)*64+n)*8+(k&7). mat 2 (Wv) -> WTv [n][k]. (r13-proven)
// ---------------------------------------------------------------------------
__global__ __launch_bounds__(256) void prep_kernel(
    const float* __restrict__ wq, const float* __restrict__ wk, const float* __restrict__ wv,
    unsigned short* __restrict__ WT2, unsigned short* __restrict__ WTv)
{
    int idx = blockIdx.x * 256 + threadIdx.x;
    int mat = idx >> 15;
    int r = idx & 32767;                        // k*64 + n
    int k = r >> 6, n = r & 63;
    const float* W = (mat == 0) ? wq : ((mat == 1) ? wk : wv);
    float s = (mat == 0) ? 0.18033688011112042f : 1.0f;  // 0.125*log2(e)
    unsigned short v = f2bfu(W[r] * s);
    if (mat < 2)
        WT2[mat * 32768 + (((k >> 3) * 64 + n) << 3) + (k & 7)] = v;
    else
        WTv[n * 512 + k] = v;
}

// ---------------------------------------------------------------------------
// Stage 1: projections (r13-proven). LDS-staged 32-row A-tiles, WT2 coalesced
// fragment loads. Grid 512: [0,256) q; [256,512) k AND vT from one emb tile.
// ---------------------------------------------------------------------------
__global__ __launch_bounds__(256) void proj_kernel(
    const float* __restrict__ x, const float* __restrict__ emb,
    const unsigned short* __restrict__ WT2, const unsigned short* __restrict__ WTv,
    unsigned short* __restrict__ qbuf, unsigned short* __restrict__ kbuf,
    unsigned short* __restrict__ vTt)
{
    __shared__ char at[32768];   // 32 rows x 512 bf16, swizzled
    const int t = threadIdx.x;
    const bool isq = blockIdx.x < 256;
    const int tile = isq ? blockIdx.x : blockIdx.x - 256;
    const float* A = isq ? x : emb;
    const int rbase = tile * 32;
    const int wave = t >> 6, lane = t & 63;
    const int lo = lane & 15, g = lane >> 4;

    #pragma unroll 4
    for (int i = 0; i < 8; ++i) {
        int pidx = i * 256 + t;
        int row = pidx >> 6, c = pidx & 63;
        const float* src = A + (size_t)(rbase + row) * IND + c * 8;
        float4 a0 = *(const float4*)src;
        float4 a1 = *(const float4*)(src + 4);
        *(bf16x8*)(at + aswz(row, c * 16)) = cvt8(a0, a1);
    }
    __syncthreads();

    {
        const int wr = wave >> 1, wc = wave & 1;
        const unsigned short* WT = WT2 + (isq ? 0 : 32768);
        const int nb = wc * 32 + lo;
        f32x4 acc[2];
        acc[0] = (f32x4){0.f, 0.f, 0.f, 0.f};
        acc[1] = (f32x4){0.f, 0.f, 0.f, 0.f};
        bf16x8 wf[2];
        #pragma unroll
        for (int nfi = 0; nfi < 2; ++nfi)
            wf[nfi] = *(const bf16x8*)(WT + ((g * 64) + nb + nfi * 16) * 8);
        #pragma unroll
        for (int ks = 0; ks < 16; ++ks) {
            bf16x8 wn[2] = {wf[0], wf[1]};
            if (ks < 15) {
                #pragma unroll
                for (int nfi = 0; nfi < 2; ++nfi)
                    wn[nfi] = *(const bf16x8*)(WT + (((ks + 1) * 4 + g) * 64 + nb + nfi * 16) * 8);
            }
            bf16x8 af = *(const bf16x8*)(at + aswz(wr * 16 + lo, (ks * 32 + g * 8) * 2));
            #pragma unroll
            for (int nfi = 0; nfi < 2; ++nfi)
                acc[nfi] = __builtin_amdgcn_mfma_f32_16x16x32_bf16(af, wf[nfi], acc[nfi], 0, 0, 0);
            wf[0] = wn[0]; wf[1] = wn[1];
        }
        unsigned short* obuf = isq ? qbuf : kbuf;
        #pragma unroll
        for (int nfi = 0; nfi < 2; ++nfi)
            #pragma unroll
            for (int r = 0; r < 4; ++r)
                obuf[(size_t)(rbase + wr * 16 + 4 * g + r) * OUTD + (wc * 2 + nfi) * 16 + lo] = f2bfu(acc[nfi][r]);
    }

    if (!isq) {
        const int f = wave * 16 + lo;
        f32x4 acc[2];
        acc[0] = (f32x4){0.f, 0.f, 0.f, 0.f};
        acc[1] = (f32x4){0.f, 0.f, 0.f, 0.f};
        bf16x8 wf = *(const bf16x8*)(WTv + f * 512 + g * 8);
        #pragma unroll
        for (int ks = 0; ks < 16; ++ks) {
            bf16x8 wn = wf;
            if (ks < 15) wn = *(const bf16x8*)(WTv + f * 512 + (ks + 1) * 32 + g * 8);
            const int k0 = ks * 32 + g * 8;
            #pragma unroll
            for (int nfi = 0; nfi < 2; ++nfi) {
                bf16x8 ef = *(const bf16x8*)(at + aswz(nfi * 16 + lo, k0 * 2));
                acc[nfi] = __builtin_amdgcn_mfma_f32_16x16x32_bf16(wf, ef, acc[nfi], 0, 0, 0);
            }
            wf = wn;
        }
        const int lop = sig4(lo);
        unsigned short* vblk = vTt + (size_t)(rbase >> 6) * 4096 + ((rbase >> 5) & 1) * 32;
        #pragma unroll
        for (int nfi = 0; nfi < 2; ++nfi)
            #pragma unroll
            for (int r = 0; r < 4; ++r)
                vblk[(wave * 16 + 4 * g + r) * 64 + nfi * 16 + lop] = f2bfu(acc[nfi][r]);
    }
}

// ---------------------------------------------------------------------------
// Stage 2: flash attention (r15-proven best). Software-pipelined, setprio,
// nsplit=8, 3-buffer LDS rotation, fixed softmax shift (C-init -16),
// VALU-tree row-sum, sigma-permuted PV K-axis.
// ---------------------------------------------------------------------------
__global__ __launch_bounds__(256) void attn_kernel(
    const unsigned short* __restrict__ qbuf, const unsigned short* __restrict__ kbuf,
    const unsigned short* __restrict__ vTt,
    unsigned short* __restrict__ Opart, float* __restrict__ Lpart)
{
    __shared__ char lds[3][16384];    // [buf][K 8K | V 8K]
    const int t = threadIdx.x;
    const int wave = t >> 6, lane = t & 63;
    const int r32 = lane & 31, hi = lane >> 5;
    const int qrow = blockIdx.x * 128 + wave * 32 + r32;
    const int split = blockIdx.y;
    const int tok0 = split * CHUNK;

    bf16x8 qf[4];
    #pragma unroll
    for (int kt = 0; kt < 4; ++kt)
        qf[kt] = *(const bf16x8*)(qbuf + (size_t)qrow * OUTD + kt * 16 + hi * 8);

    f32x16 o0 = (f32x16)(0.f), o1 = (f32x16)(0.f);
    float l_run = 0.f;

    uint4 a0, a1, b0, b1;
    auto LOADT = [&](int tb) {
        const uint4* ks = (const uint4*)(kbuf + (size_t)tb * 64);
        const uint4* vs = (const uint4*)(vTt + (size_t)tb * 64);
        a0 = ks[t]; a1 = ks[t + 256]; b0 = vs[t]; b1 = vs[t + 256];
    };
    auto WRITET = [&](char* base) {
        *(uint4*)(base + swz(t >> 3, t & 7)) = a0;
        *(uint4*)(base + swz((t + 256) >> 3, t & 7)) = a1;
        *(uint4*)(base + 8192 + swz(t >> 3, t & 7)) = b0;
        *(uint4*)(base + 8192 + swz((t + 256) >> 3, t & 7)) = b1;
    };
    auto QK = [&](const char* kb, f32x16& sA, f32x16& sB) {
        bf16x8 kA[4], kB[4];
        #pragma unroll
        for (int kt = 0; kt < 4; ++kt) {
            const int c = kt * 2 + hi;
            kA[kt] = *(const bf16x8*)(kb + swz(r32, c));
            kB[kt] = *(const bf16x8*)(kb + swz(32 + r32, c));
        }
        sA = (f32x16)(-16.f); sB = (f32x16)(-16.f);
        __builtin_amdgcn_s_setprio(1);
        #pragma unroll
        for (int kt = 0; kt < 4; ++kt) {
            sA = __builtin_amdgcn_mfma_f32_32x32x16_bf16(kA[kt], qf[kt], sA, 0, 0, 0);
            sB = __builtin_amdgcn_mfma_f32_32x32x16_bf16(kB[kt], qf[kt], sB, 0, 0, 0);
        }
        __builtin_amdgcn_s_setprio(0);
    };
    auto SOFTPV = [&](f32x16& sA, f32x16& sB, const char* vb) {
        #pragma unroll
        for (int r = 0; r < 16; ++r) {
            sA[r] = __builtin_amdgcn_exp2f(sA[r]);
            sB[r] = __builtin_amdgcn_exp2f(sB[r]);
        }
        {
            float a8[8], b8[8], a4[4], b4[4];
            #pragma unroll
            for (int j = 0; j < 8; ++j) {
                a8[j] = sA[2 * j] + sA[2 * j + 1];
                b8[j] = sB[2 * j] + sB[2 * j + 1];
            }
            #pragma unroll
            for (int j = 0; j < 4; ++j) {
                a4[j] = a8[2 * j] + a8[2 * j + 1];
                b4[j] = b8[2 * j] + b8[2 * j + 1];
            }
            l_run += ((a4[0] + a4[1]) + (a4[2] + a4[3]))
                   + ((b4[0] + b4[1]) + (b4[2] + b4[3]));
        }
        union { uint32_t u[4]; bf16x8 v; } pA0, pA1, pB0, pB1;
        #pragma unroll
        for (int j = 0; j < 4; ++j) {
            pA0.u[j] = pkbf(sA[2 * j], sA[2 * j + 1]);
            pA1.u[j] = pkbf(sA[8 + 2 * j], sA[9 + 2 * j]);
            pB0.u[j] = pkbf(sB[2 * j], sB[2 * j + 1]);
            pB1.u[j] = pkbf(sB[8 + 2 * j], sB[9 + 2 * j]);
        }
        bf16x8 vA[4], vB[4];
        #pragma unroll
        for (int ft = 0; ft < 2; ++ft)
            #pragma unroll
            for (int kt = 0; kt < 2; ++kt) {
                const int row = ft * 32 + r32;
                vA[ft * 2 + kt] = *(const bf16x8*)(vb + swz(row, kt * 2 + hi));
                vB[ft * 2 + kt] = *(const bf16x8*)(vb + swz(row, 4 + kt * 2 + hi));
            }
        __builtin_amdgcn_s_setprio(1);
        o0 = __builtin_amdgcn_mfma_f32_32x32x16_bf16(vA[0], pA0.v, o0, 0, 0, 0);
        o1 = __builtin_amdgcn_mfma_f32_32x32x16_bf16(vA[2], pA0.v, o1, 0, 0, 0);
        o0 = __builtin_amdgcn_mfma_f32_32x32x16_bf16(vA[1], pA1.v, o0, 0, 0, 0);
        o1 = __builtin_amdgcn_mfma_f32_32x32x16_bf16(vA[3], pA1.v, o1, 0, 0, 0);
        o0 = __builtin_amdgcn_mfma_f32_32x32x16_bf16(vB[0], pB0.v, o0, 0, 0, 0);
        o1 = __builtin_amdgcn_mfma_f32_32x32x16_bf16(vB[2], pB0.v, o1, 0, 0, 0);
        o0 = __builtin_amdgcn_mfma_f32_32x32x16_bf16(vB[1], pB1.v, o0, 0, 0, 0);
        o1 = __builtin_amdgcn_mfma_f32_32x32x16_bf16(vB[3], pB1.v, o1, 0, 0, 0);
        __builtin_amdgcn_s_setprio(0);
    };

    // prologue: tile0 -> buf0; QK(0); tile1 -> buf1
    LOADT(tok0);
    WRITET(&lds[0][0]);
    __syncthreads();
    LOADT(tok0 + 64);
    f32x16 sPA, sPB;
    QK(&lds[0][0], sPA, sPB);
    WRITET(&lds[1][0]);

    #pragma unroll
    for (int it = 1; it < NITER; ++it) {
        __syncthreads();   // tile it visible; buf (it+1)%3's readers done
        const bool have = (it + 1 < NITER);
        if (have) LOADT(tok0 + (it + 1) * 64);
        f32x16 sNA, sNB;
        QK(&lds[it % 3][0], sNA, sNB);                  // MFMAs in flight...
        SOFTPV(sPA, sPB, &lds[(it - 1) % 3][0] + 8192); // ...while VALU works
        if (have) WRITET(&lds[(it + 1) % 3][0]);
        sPA = sNA; sPB = sNB;
    }
    SOFTPV(sPA, sPB, &lds[(NITER - 1) % 3][0] + 8192);

    float l = l_run + __shfl_xor(l_run, 32);
    if (hi == 0)
        Lpart[(size_t)split * NDEC + qrow] = l;
    unsigned short* orow = Opart + ((size_t)split * NDEC + qrow) * OUTD;
    #pragma unroll
    for (int q = 0; q < 4; ++q) {
        uint2 st0, st1;
        st0.x = pkbf(o0[q * 4 + 0], o0[q * 4 + 1]);
        st0.y = pkbf(o0[q * 4 + 2], o0[q * 4 + 3]);
        st1.x = pkbf(o1[q * 4 + 0], o1[q * 4 + 1]);
        st1.y = pkbf(o1[q * 4 + 2], o1[q * 4 + 3]);
        *(uint2*)(orow + q * 8 + hi * 4) = st0;
        *(uint2*)(orow + 32 + q * 8 + hi * 4) = st1;
    }
}

// ---------------------------------------------------------------------------
// Stage 3: combine splits and normalize.
// ---------------------------------------------------------------------------
__global__ __launch_bounds__(256) void combine_kernel(
    const unsigned short* __restrict__ Opart, const float* __restrict__ Lpart,
    float* __restrict__ out)
{
    int idx = blockIdx.x * 256 + threadIdx.x;
    int row = idx >> 3;
    int fo = (idx & 7) * 8;
    float L = 0.f;
    float acc[8];
    #pragma unroll
    for (int j = 0; j < 8; ++j) acc[j] = 0.f;
    #pragma unroll
    for (int s = 0; s < NSPLIT; ++s) {
        L += Lpart[(size_t)s * NDEC + row];
        uint4 v = *(const uint4*)(Opart + ((size_t)s * NDEC + row) * OUTD + fo);
        uint32_t u[4] = {v.x, v.y, v.z, v.w};
        #pragma unroll
        for (int j = 0; j < 4; ++j) {
            union { uint32_t u; float f; } lo2, hi2;
            lo2.u = u[j] << 16;
            hi2.u = u[j] & 0xFFFF0000u;
            acc[2 * j]     += lo2.f;
            acc[2 * j + 1] += hi2.f;
        }
    }
    float inv = 1.f / L;
    float4 s0, s1;
    s0.x = acc[0] * inv; s0.y = acc[1] * inv; s0.z = acc[2] * inv; s0.w = acc[3] * inv;
    s1.x = acc[4] * inv; s1.y = acc[5] * inv; s1.z = acc[6] * inv; s1.w = acc[7] * inv;
    *(float4*)(out + (size_t)row * OUTD + fo) = s0;
    *(float4*)(out + (size_t)row * OUTD + fo + 4) = s1;
}

extern "C" void kernel_launch(void* const* d_in, const int* in_sizes, int n_in,
                              void* d_out, int out_size, void* d_ws, size_t ws_size,
                              hipStream_t stream) {
    const float* x   = (const float*)d_in[0];
    const float* emb = (const float*)d_in[1];
    const float* wq  = (const float*)d_in[2];
    const float* wk  = (const float*)d_in[3];
    const float* wv  = (const float*)d_in[4];
    float* out = (float*)d_out;
    char* ws = (char*)d_ws;

    unsigned short* qbuf = (unsigned short*)ws;                          // 1 MiB
    unsigned short* kbuf = (unsigned short*)(ws + (1u << 20));           // 1 MiB
    unsigned short* vTt  = (unsigned short*)(ws + (2u << 20));           // 1 MiB
    unsigned short* WT2  = (unsigned short*)(ws + (3u << 20));           // 128 KiB
    unsigned short* WTv  = (unsigned short*)(ws + (3u << 20) + (128u << 10)); // 64 KiB
    const size_t obase = (3u << 20) + (256u << 10);
    unsigned short* Opart = (unsigned short*)(ws + obase);               // 8 MiB
    float* Lpart = (float*)(ws + obase + (size_t)NSPLIT * NDEC * OUTD * 2);

    hipLaunchKernelGGL(prep_kernel, dim3(384), dim3(256), 0, stream, wq, wk, wv, WT2, WTv);
    hipLaunchKernelGGL(proj_kernel, dim3(512), dim3(256), 0, stream,
                       x, emb, WT2, WTv, qbuf, kbuf, vTt);
    hipLaunchKernelGGL(attn_kernel, dim3(NDEC / 128, NSPLIT), dim3(256), 0, stream,
                       qbuf, kbuf, vTt, Opart, Lpart);
    hipLaunchKernelGGL(combine_kernel, dim3((NDEC * 8) / 256), dim3(256), 0, stream,
                       Opart, Lpart, out);
}